// Round 20
// baseline (183.494 us; speedup 1.0000x reference)
//
#include <hip/hip_runtime.h>
#include <math.h>

typedef __attribute__((ext_vector_type(8))) short short8;
typedef __attribute__((ext_vector_type(4))) float f32x4;

__device__ __forceinline__ short f2bf(float f) {
    union { float f; unsigned u; } v; v.f = f;
    unsigned r = v.u + 0x7fff + ((v.u >> 16) & 1);
    return (short)(r >> 16);
}
__device__ __forceinline__ float b2f(short s) {
    union { unsigned u; float f; } v;
    v.u = ((unsigned)(unsigned short)s) << 16;
    return v.f;
}

// async global->LDS, 16B per lane; lds base must be wave-uniform.
__device__ __forceinline__ void gload16(const short* g, short* l) {
    __builtin_amdgcn_global_load_lds(
        (const __attribute__((address_space(1))) unsigned int*)g,
        (__attribute__((address_space(3))) unsigned int*)l,
        16, 0, 0);
}

// ---------------------------------------------------------------------------
// prep: x->bf16 (blocks 0..2047), weight transposes (2048..5119), bias pack.
// ---------------------------------------------------------------------------
__global__ __launch_bounds__(256) void prep_kernel(
    const float* __restrict__ x, short* __restrict__ xb,
    const float* __restrict__ Wq, const float* __restrict__ Wk,
    const float* __restrict__ Wv, const float* __restrict__ Wo,
    const float* __restrict__ W1, const float* __restrict__ W2,
    short* __restrict__ Wqkv_t, short* __restrict__ Wo_t,
    short* __restrict__ W1_t, short* __restrict__ W2_t,
    const float* __restrict__ bq, const float* __restrict__ bk,
    const float* __restrict__ bv, float* __restrict__ qbias)
{
    int bid = blockIdx.x;
    if (bid < 2048) {
        int i = (bid * 256 + threadIdx.x) * 4;
        float4 v = *reinterpret_cast<const float4*>(&x[i]);
        short4 o;
        o.x = f2bf(v.x); o.y = f2bf(v.y); o.z = f2bf(v.z); o.w = f2bf(v.w);
        *reinterpret_cast<short4*>(&xb[i]) = o;
        return;
    }
    if (bid < 5120) {
        int t = bid - 2048;
        const float* W; short* Wt; int K, N, nbx, loc;
        if (t < 1024) {
            int j = t >> 8; loc = t & 255; K = 512; N = 512; nbx = 16;
            W  = (j == 0) ? Wq : (j == 1) ? Wk : (j == 2) ? Wv : Wo;
            Wt = (j == 0) ? Wqkv_t : (j == 1) ? Wqkv_t + 512 * 512
               : (j == 2) ? Wqkv_t + 1024 * 512 : Wo_t;
        } else if (t < 2048) {
            loc = t - 1024; W = W1; Wt = W1_t; K = 512; N = 2048; nbx = 16;
        } else {
            loc = t - 2048; W = W2; Wt = W2_t; K = 2048; N = 512; nbx = 64;
        }
        int k0 = (loc % nbx) * 32, n0 = (loc / nbx) * 32;
        __shared__ float tl[32][33];
        int tx = threadIdx.x & 31, ty = threadIdx.x >> 5;
#pragma unroll
        for (int r = ty; r < 32; r += 8)
            tl[r][tx] = W[(size_t)(k0 + r) * N + n0 + tx];
        __syncthreads();
        // short2 stores: thread -> (row rr, k-pair kk)
        int kk = (threadIdx.x & 15) * 2;
#pragma unroll
        for (int rr = (threadIdx.x >> 4); rr < 32; rr += 16) {
            short2 s;
            s.x = f2bf(tl[kk][rr]);
            s.y = f2bf(tl[kk + 1][rr]);
            *(short2*)&Wt[(size_t)(n0 + rr) * K + k0 + kk] = s;
        }
        return;
    }
    {
        int i = (bid - 5120) * 256 + threadIdx.x;
        if (i < 1536)
            qbias[i] = (i < 512) ? bq[i] : (i < 1024 ? bk[i - 512] : bv[i - 1024]);
    }
}

// ---------------------------------------------------------------------------
// bf16 MFMA GEMM (single-buffered, 2 barriers/K-iter, gload_lds staging) with
// coalesced two-pass epilogue (acc->LDS bf16->short8 stores, vector resid).
// BM = MI*32, BN = NI*32, BK = 64, 4 waves (2x2). bf16 output only.
// ---------------------------------------------------------------------------
template<int MI, int NI>
__global__ __launch_bounds__(256) void gemm2(
    const short* __restrict__ A, int lda,
    const short* __restrict__ Bt, int ldb,
    const float* __restrict__ bias,
    const float* __restrict__ residf,
    const short* __restrict__ residb,
    short* __restrict__ Cb,
    int N, int K, int relu)
{
    constexpr int BM = MI * 32;
    constexpr int BN = NI * 32;
    __shared__ short smem[BM * 64 + BN * 64];
    short* Ash = smem;
    short* Bsh = smem + BM * 64;
    int tid = threadIdx.x;
    int wid = tid >> 6, lane = tid & 63;
    int g = lane >> 4, c = lane & 15;
    int wm = wid >> 1, wn = wid & 1;
    size_t m0 = (size_t)blockIdx.x * BM;
    size_t n0 = (size_t)blockIdx.y * BN;
    int lrow = lane >> 3;          // 0..7
    int lcol = (lane & 7) * 8;     // shorts (16B granule)

    f32x4 acc[MI][NI];
#pragma unroll
    for (int i = 0; i < MI; ++i)
#pragma unroll
        for (int j = 0; j < NI; ++j)
            acc[i][j] = (f32x4){0.f, 0.f, 0.f, 0.f};

    for (int k0 = 0; k0 < K; k0 += 64) {
        __syncthreads();
#pragma unroll
        for (int i = 0; i < MI; ++i) {
            int chunk = wid * MI + i; int row = chunk * 8 + lrow;
            gload16(A + (m0 + row) * lda + k0 + lcol, Ash + chunk * 512);
        }
#pragma unroll
        for (int i = 0; i < NI; ++i) {
            int chunk = wid * NI + i; int row = chunk * 8 + lrow;
            gload16(Bt + (n0 + row) * ldb + k0 + lcol, Bsh + chunk * 512);
        }
        __syncthreads();

        short8 a[MI][2], b[NI][2];
#pragma unroll
        for (int kc = 0; kc < 2; ++kc) {
#pragma unroll
            for (int mi = 0; mi < MI; ++mi)
                a[mi][kc] = *(const short8*)&Ash[(wm * MI * 16 + mi * 16 + c) * 64 + kc * 32 + g * 8];
#pragma unroll
            for (int ni = 0; ni < NI; ++ni)
                b[ni][kc] = *(const short8*)&Bsh[(wn * NI * 16 + ni * 16 + c) * 64 + kc * 32 + g * 8];
        }
#pragma unroll
        for (int kc = 0; kc < 2; ++kc)
#pragma unroll
            for (int mi = 0; mi < MI; ++mi)
#pragma unroll
                for (int ni = 0; ni < NI; ++ni)
                    acc[mi][ni] = __builtin_amdgcn_mfma_f32_16x16x32_bf16(
                        a[mi][kc], b[ni][kc], acc[mi][ni], 0, 0, 0);
    }

    // ---- epilogue pass 1: acc (+bias) -> LDS bf16 [BM][BN] ----
    __syncthreads();                 // staging reads done; reuse smem
    short* Cl = smem;
#pragma unroll
    for (int mi = 0; mi < MI; ++mi)
#pragma unroll
        for (int ni = 0; ni < NI; ++ni)
#pragma unroll
            for (int r = 0; r < 4; ++r) {
                int rl = wm * (MI * 16) + mi * 16 + g * 4 + r;
                int cl = wn * (NI * 16) + ni * 16 + c;
                float v = acc[mi][ni][r];
                if (bias) v += bias[n0 + cl];
                Cl[rl * BN + cl] = f2bf(v);
            }
    __syncthreads();

    // ---- epilogue pass 2: coalesced short8 stores + vector resid/relu ----
    constexpr int TOT = BM * BN;
#pragma unroll
    for (int i = tid * 8; i < TOT; i += 2048) {
        int row = i / BN, col = i - (i / BN) * BN;
        size_t gidx = (m0 + row) * (size_t)N + n0 + col;
        short8 vv = *(const short8*)&Cl[i];
        if (residf || residb || relu) {
            float tmp[8];
#pragma unroll
            for (int j = 0; j < 8; ++j) tmp[j] = b2f(vv[j]);
            if (residf) {
                float4 ra = *(const float4*)&residf[gidx];
                float4 rb = *(const float4*)&residf[gidx + 4];
                tmp[0] += ra.x; tmp[1] += ra.y; tmp[2] += ra.z; tmp[3] += ra.w;
                tmp[4] += rb.x; tmp[5] += rb.y; tmp[6] += rb.z; tmp[7] += rb.w;
            }
            if (residb) {
                short8 rr = *(const short8*)&residb[gidx];
#pragma unroll
                for (int j = 0; j < 8; ++j) tmp[j] += b2f(rr[j]);
            }
            if (relu)
#pragma unroll
                for (int j = 0; j < 8; ++j) tmp[j] = fmaxf(tmp[j], 0.f);
#pragma unroll
            for (int j = 0; j < 8; ++j) vv[j] = f2bf(tmp[j]);
        }
        *(short8*)&Cb[gidx] = vv;
    }
}

// ---------------------------------------------------------------------------
// Fused flash attention + full heatmap (R18/R19 structure, plain heat stores)
// + coalesced wv write through LDS.
// ---------------------------------------------------------------------------
__global__ __launch_bounds__(256) void attn_kernel(
    const short* __restrict__ QKV,
    float* __restrict__ heat,
    short* __restrict__ wv)
{
    constexpr int S = 2048, LD = 1536;
    __shared__ short Kl[2][4096];      // [buf][t][64] linear, 128B rows
    __shared__ short Vt[2][64][72];    // [buf][v][t]
    __shared__ short Pl[4][16][72];    // per-wave P, [s][t]

    int tid = threadIdx.x, wid = tid >> 6, lane = tid & 63;
    int g = lane >> 4, c = lane & 15, g4 = g * 4;
    int id = blockIdx.x;
    int xcd = id & 7, k = id >> 3;
    int hb = (xcd << 1) | (k >> 5);
    int sb = k & 31;
    int by = (sb & 1) ? (31 - (sb >> 1)) : (sb >> 1);
    int h = hb >> 1, b = hb & 1;
    int s0 = by * 64, sbase = s0 + wid * 16, sglob = sbase + c;

    const short* qp = QKV + (size_t)(b * S + sglob) * LD + h * 64 + g * 8;
    short8 q0 = *(const short8*)qp, q1 = *(const short8*)(qp + 32);

    f32x4 o[4];
#pragma unroll
    for (int ni = 0; ni < 4; ++ni) o[ni] = (f32x4){0.f, 0.f, 0.f, 0.f};
    float m_run = -1e30f, l_run = 0.f;

    const short* kb_base = QKV + (size_t)b * S * LD + 512 + h * 64;
    int vrow = tid >> 2, vch = tid & 3;
    const short* vb_base = QKV + (size_t)b * S * LD + 1024 + h * 64 + vch * 16;

    auto stageK = [&](int tt, int buf) {
        int j = lane & 7, rr = lane >> 3;
#pragma unroll
        for (int i = 0; i < 2; ++i) {
            int chunk = wid * 2 + i;
            int row = chunk * 8 + rr;
            gload16(kb_base + (size_t)(tt * 64 + row) * LD + j * 8,
                    &Kl[buf][chunk * 512]);
        }
    };
    auto loadK = [&](int tt, short8 dst[4][2]) {
#pragma unroll
        for (int ni = 0; ni < 4; ++ni)
#pragma unroll
            for (int kc = 0; kc < 2; ++kc)
                dst[ni][kc] = *(const short8*)(kb_base +
                    (size_t)(tt * 64 + ni * 16 + c) * LD + kc * 32 + g * 8);
    };

    stageK(0, 0);
    short8 va, vb2;
    {
        const short* vp = vb_base + (size_t)vrow * LD;
        va = *(const short8*)vp; vb2 = *(const short8*)(vp + 8);
    }
    __syncthreads();   // K(0) staged

    // ---- causal phase: tiles 0..by, 1 barrier/tile ----
    for (int tt = 0; tt <= by; ++tt) {
        int cur = tt & 1;
#pragma unroll
        for (int j = 0; j < 8; ++j) Vt[cur][vch * 16 + j][vrow] = va[j];
#pragma unroll
        for (int j = 0; j < 8; ++j) Vt[cur][vch * 16 + 8 + j][vrow] = vb2[j];

        short8 vna, vnb;
        if (tt < by) {
            stageK(tt + 1, cur ^ 1);   // async; drained by this tile's barrier
            const short* vp = vb_base + (size_t)((tt + 1) * 64 + vrow) * LD;
            vna = *(const short8*)vp; vnb = *(const short8*)(vp + 8);
        }

        short8 kf[4][2];
#pragma unroll
        for (int ni = 0; ni < 4; ++ni)
#pragma unroll
            for (int kc = 0; kc < 2; ++kc)
                kf[ni][kc] = *(const short8*)&Kl[cur][(ni * 16 + c) * 64 + kc * 32 + g * 8];

        int t0 = tt * 64;
        f32x4 sacc[4];
#pragma unroll
        for (int ni = 0; ni < 4; ++ni) {
            sacc[ni] = (f32x4){0.f, 0.f, 0.f, 0.f};
            sacc[ni] = __builtin_amdgcn_mfma_f32_16x16x32_bf16(kf[ni][0], q0, sacc[ni], 0, 0, 0);
            sacc[ni] = __builtin_amdgcn_mfma_f32_16x16x32_bf16(kf[ni][1], q1, sacc[ni], 0, 0, 0);
        }
#pragma unroll
        for (int ni = 0; ni < 4; ++ni)
            *(f32x4*)&heat[((size_t)hb * S + sglob) * S + t0 + ni * 16 + g4] = sacc[ni];

        float tm = -1e30f;
        if (tt == by) {   // diagonal tile: mask
#pragma unroll
            for (int ni = 0; ni < 4; ++ni)
#pragma unroll
                for (int r = 0; r < 4; ++r) {
                    int t = t0 + ni * 16 + g4 + r;
                    float v = (t <= sglob) ? sacc[ni][r] : -1e30f;
                    sacc[ni][r] = v;
                    tm = fmaxf(tm, v);
                }
        } else {          // interior: fully causal
#pragma unroll
            for (int ni = 0; ni < 4; ++ni)
#pragma unroll
                for (int r = 0; r < 4; ++r)
                    tm = fmaxf(tm, sacc[ni][r]);
        }
        tm = fmaxf(tm, __shfl_xor(tm, 16));
        tm = fmaxf(tm, __shfl_xor(tm, 32));

        float mn = fmaxf(m_run, tm);
        float sc = __expf(m_run - mn);
        m_run = mn;
        float ps = 0.f;
#pragma unroll
        for (int ni = 0; ni < 4; ++ni)
#pragma unroll
            for (int r = 0; r < 4; ++r) {
                float p = __expf(sacc[ni][r] - mn);
                sacc[ni][r] = p;
                ps += p;
            }
        ps += __shfl_xor(ps, 16);
        ps += __shfl_xor(ps, 32);
        l_run = l_run * sc + ps;

        float scr[4];
#pragma unroll
        for (int r = 0; r < 4; ++r) scr[r] = __shfl(sc, g4 + r, 64);
#pragma unroll
        for (int ni = 0; ni < 4; ++ni)
#pragma unroll
            for (int r = 0; r < 4; ++r)
                o[ni][r] *= scr[r];

#pragma unroll
        for (int ni = 0; ni < 4; ++ni) {
            short4 pw;
            pw.x = f2bf(sacc[ni][0]); pw.y = f2bf(sacc[ni][1]);
            pw.z = f2bf(sacc[ni][2]); pw.w = f2bf(sacc[ni][3]);
            *reinterpret_cast<short4*>(&Pl[wid][c][ni * 16 + g4]) = pw;
        }

        __syncthreads();   // Vt[cur]+Pl visible; K(tt+1) gload drained

        short8 pa0 = *reinterpret_cast<const short8*>(&Pl[wid][c][g * 8]);
        short8 pa1 = *reinterpret_cast<const short8*>(&Pl[wid][c][32 + g * 8]);
#pragma unroll
        for (int ni = 0; ni < 4; ++ni) {
            short8 vb0 = *reinterpret_cast<const short8*>(&Vt[cur][ni * 16 + c][g * 8]);
            short8 vb1 = *reinterpret_cast<const short8*>(&Vt[cur][ni * 16 + c][32 + g * 8]);
            o[ni] = __builtin_amdgcn_mfma_f32_16x16x32_bf16(pa0, vb0, o[ni], 0, 0, 0);
            o[ni] = __builtin_amdgcn_mfma_f32_16x16x32_bf16(pa1, vb1, o[ni], 0, 0, 0);
        }

        if (tt < by) { va = vna; vb2 = vnb; }
    }

    // ---- coalesced wv write: scatter to LDS (Kl[0] is dead), then short8 ----
    {
        float linv[4];
#pragma unroll
        for (int r = 0; r < 4; ++r) linv[r] = 1.0f / __shfl(l_run, g4 + r, 64);
        short* Wl = &Kl[0][0];   // 64x64 shorts
#pragma unroll
        for (int ni = 0; ni < 4; ++ni)
#pragma unroll
            for (int r = 0; r < 4; ++r)
                Wl[(wid * 16 + g4 + r) * 64 + ni * 16 + c] = f2bf(o[ni][r] * linv[r]);
        __syncthreads();
        int row = tid >> 2, col = (tid & 3) * 16;
        size_t gbase = (size_t)(b * S + s0 + row) * 512 + h * 64 + col;
        *(short8*)&wv[gbase]     = *(const short8*)&Wl[row * 64 + col];
        *(short8*)&wv[gbase + 8] = *(const short8*)&Wl[row * 64 + col + 8];
    }

    // ---- streaming phase: t-split across waves ----
    short8 qa[4][2];
#pragma unroll
    for (int si = 0; si < 4; ++si) {
        const short* qps = QKV + (size_t)(b * S + s0 + si * 16 + c) * LD + h * 64 + g * 8;
        qa[si][0] = *(const short8*)qps;
        qa[si][1] = *(const short8*)(qps + 32);
    }

    for (int tt = by + 1 + wid; tt < 32; tt += 4) {
        int t0 = tt * 64;
        short8 kf[4][2];
        loadK(tt, kf);
        f32x4 sc4[4][4];
#pragma unroll
        for (int si = 0; si < 4; ++si)
#pragma unroll
            for (int ni = 0; ni < 4; ++ni) {
                sc4[si][ni] = (f32x4){0.f, 0.f, 0.f, 0.f};
                sc4[si][ni] = __builtin_amdgcn_mfma_f32_16x16x32_bf16(
                    kf[ni][0], qa[si][0], sc4[si][ni], 0, 0, 0);
                sc4[si][ni] = __builtin_amdgcn_mfma_f32_16x16x32_bf16(
                    kf[ni][1], qa[si][1], sc4[si][ni], 0, 0, 0);
            }
#pragma unroll
        for (int si = 0; si < 4; ++si)
#pragma unroll
            for (int ni = 0; ni < 4; ++ni)
                *(f32x4*)&heat[((size_t)hb * S + s0 + si * 16 + c) * S + t0 + ni * 16 + g4] = sc4[si][ni];
    }
}

// ---------------------------------------------------------------------------
// LayerNorm over last dim 512, bf16 input; fp32 and/or bf16 output.
// ---------------------------------------------------------------------------
__device__ __forceinline__ float block_sum256(float v, float* sm) {
#pragma unroll
    for (int off = 32; off; off >>= 1) v += __shfl_down(v, off);
    __syncthreads();
    if ((threadIdx.x & 63) == 0) sm[threadIdx.x >> 6] = v;
    __syncthreads();
    return sm[0] + sm[1] + sm[2] + sm[3];
}

__global__ __launch_bounds__(256) void ln_kernel(
    const short* __restrict__ in, const float* __restrict__ g,
    const float* __restrict__ bta, float* __restrict__ outf,
    short* __restrict__ outb)
{
    __shared__ float sm[4];
    int row = blockIdx.x, tid = threadIdx.x;
    const short* r = in + (size_t)row * 512;
    float v0 = b2f(r[tid]), v1 = b2f(r[tid + 256]);
    float mu = block_sum256(v0 + v1, sm) * (1.f / 512.f);
    float d0 = v0 - mu, d1 = v1 - mu;
    float var = block_sum256(d0 * d0 + d1 * d1, sm) * (1.f / 512.f);
    float rs = rsqrtf(var + 1e-5f);
    float o0 = d0 * rs * g[tid] + bta[tid];
    float o1 = d1 * rs * g[tid + 256] + bta[tid + 256];
    if (outf) {
        outf[(size_t)row * 512 + tid]       = o0;
        outf[(size_t)row * 512 + tid + 256] = o1;
    }
    if (outb) {
        outb[(size_t)row * 512 + tid]       = f2bf(o0);
        outb[(size_t)row * 512 + tid + 256] = f2bf(o1);
    }
}

// ---------------------------------------------------------------------------
extern "C" void kernel_launch(void* const* d_in, const int* in_sizes, int n_in,
                              void* d_out, int out_size, void* d_ws, size_t ws_size,
                              hipStream_t stream)
{
    const float* x    = (const float*)d_in[0];
    const float* Wq   = (const float*)d_in[1];
    const float* bq   = (const float*)d_in[2];
    const float* Wk   = (const float*)d_in[3];
    const float* bk   = (const float*)d_in[4];
    const float* Wv   = (const float*)d_in[5];
    const float* bv   = (const float*)d_in[6];
    const float* Wo   = (const float*)d_in[7];
    const float* bo   = (const float*)d_in[8];
    const float* W1   = (const float*)d_in[9];
    const float* b1   = (const float*)d_in[10];
    const float* W2   = (const float*)d_in[11];
    const float* b2   = (const float*)d_in[12];
    const float* ln1g = (const float*)d_in[13];
    const float* ln1b = (const float*)d_in[14];
    const float* ln2g = (const float*)d_in[15];
    const float* ln2b = (const float*)d_in[16];

    const int T = 4096;

    char* w = (char*)d_ws;
    short* xb     = (short*)(w);                     // [0,4M)
    short* QKVb   = (short*)(w + 4194304);           // [4M,16M)
    short* wvb    = (short*)(w + 16777216);          // [16M,20M)
    short* tmpb   = (short*)(w + 20971520);          // [20M,24M) bf16
    short* x1b    = (short*)(w + 25165824);          // [24M,28M)
    short* tmpb2  = (short*)(w + 29360128);          // [28M,32M)
    short* Wqkv_t = (short*)(w + 33554432);          // [32M,33.5M)
    short* Wo_t   = (short*)(w + 35127296);
    short* W1_t   = (short*)(w + 35651584);
    short* W2_t   = (short*)(w + 37748736);
    float* qbias  = (float*)(w + 39845888);
    short* hidb   = (short*)(w);                     // aliases xb+QKVb (dead by FFN1)

    float* out_x2 = (float*)d_out;
    float* heat   = out_x2 + (size_t)T * 512;

    prep_kernel<<<dim3(5126), 256, 0, stream>>>(
        x, xb, Wq, Wk, Wv, Wo, W1, W2,
        Wqkv_t, Wo_t, W1_t, W2_t, bq, bk, bv, qbias);

    // QKV projection (combined, N=1536)
    gemm2<2, 4><<<dim3(64, 12), 256, 0, stream>>>(
        xb, 512, Wqkv_t, 512, qbias, nullptr, nullptr, QKVb, 1536, 512, 0);

    // fused attention + heatmap
    attn_kernel<<<dim3(512), 256, 0, stream>>>(QKVb, heat, wvb);

    // Wo projection + residual (bf16 xb), bf16 out
    gemm2<2, 2><<<dim3(64, 8), 256, 0, stream>>>(
        wvb, 512, Wo_t, 512, bo, nullptr, xb, tmpb, 512, 512, 0);
    ln_kernel<<<dim3(T), 256, 0, stream>>>(tmpb, ln1g, ln1b, nullptr, x1b);

    // FFN
    gemm2<2, 4><<<dim3(64, 16), 256, 0, stream>>>(
        x1b, 512, W1_t, 512, b1, nullptr, nullptr, hidb, 2048, 512, 1);
    gemm2<2, 2><<<dim3(64, 8), 256, 0, stream>>>(
        hidb, 2048, W2_t, 2048, b2, nullptr, x1b, tmpb2, 512, 2048, 0);
    ln_kernel<<<dim3(T), 256, 0, stream>>>(tmpb2, ln2g, ln2b, out_x2, nullptr);
}

// Round 21
// 180.028 us; speedup vs baseline: 1.0193x; 1.0193x over previous
//
#include <hip/hip_runtime.h>
#include <math.h>

typedef __attribute__((ext_vector_type(8))) short short8;
typedef __attribute__((ext_vector_type(4))) float f32x4;

__device__ __forceinline__ short f2bf(float f) {
    union { float f; unsigned u; } v; v.f = f;
    unsigned r = v.u + 0x7fff + ((v.u >> 16) & 1);
    return (short)(r >> 16);
}
__device__ __forceinline__ float b2f(short s) {
    union { unsigned u; float f; } v;
    v.u = ((unsigned)(unsigned short)s) << 16;
    return v.f;
}

// async global->LDS, 16B per lane; lds base must be wave-uniform.
__device__ __forceinline__ void gload16(const short* g, short* l) {
    __builtin_amdgcn_global_load_lds(
        (const __attribute__((address_space(1))) unsigned int*)g,
        (__attribute__((address_space(3))) unsigned int*)l,
        16, 0, 0);
}

// ---------------------------------------------------------------------------
// prep: x->bf16 (blocks 0..2047), weight transposes (2048..5119), bias pack.
// ---------------------------------------------------------------------------
__global__ __launch_bounds__(256) void prep_kernel(
    const float* __restrict__ x, short* __restrict__ xb,
    const float* __restrict__ Wq, const float* __restrict__ Wk,
    const float* __restrict__ Wv, const float* __restrict__ Wo,
    const float* __restrict__ W1, const float* __restrict__ W2,
    short* __restrict__ Wqkv_t, short* __restrict__ Wo_t,
    short* __restrict__ W1_t, short* __restrict__ W2_t,
    const float* __restrict__ bq, const float* __restrict__ bk,
    const float* __restrict__ bv, float* __restrict__ qbias)
{
    int bid = blockIdx.x;
    if (bid < 2048) {
        int i = (bid * 256 + threadIdx.x) * 4;
        float4 v = *reinterpret_cast<const float4*>(&x[i]);
        short4 o;
        o.x = f2bf(v.x); o.y = f2bf(v.y); o.z = f2bf(v.z); o.w = f2bf(v.w);
        *reinterpret_cast<short4*>(&xb[i]) = o;
        return;
    }
    if (bid < 5120) {
        int t = bid - 2048;
        const float* W; short* Wt; int K, N, nbx, loc;
        if (t < 1024) {
            int j = t >> 8; loc = t & 255; K = 512; N = 512; nbx = 16;
            W  = (j == 0) ? Wq : (j == 1) ? Wk : (j == 2) ? Wv : Wo;
            Wt = (j == 0) ? Wqkv_t : (j == 1) ? Wqkv_t + 512 * 512
               : (j == 2) ? Wqkv_t + 1024 * 512 : Wo_t;
        } else if (t < 2048) {
            loc = t - 1024; W = W1; Wt = W1_t; K = 512; N = 2048; nbx = 16;
        } else {
            loc = t - 2048; W = W2; Wt = W2_t; K = 2048; N = 512; nbx = 64;
        }
        int k0 = (loc % nbx) * 32, n0 = (loc / nbx) * 32;
        __shared__ float tl[32][33];
        int tx = threadIdx.x & 31, ty = threadIdx.x >> 5;
#pragma unroll
        for (int r = ty; r < 32; r += 8)
            tl[r][tx] = W[(size_t)(k0 + r) * N + n0 + tx];
        __syncthreads();
#pragma unroll
        for (int r = ty; r < 32; r += 8)
            Wt[(size_t)(n0 + r) * K + k0 + tx] = f2bf(tl[tx][r]);
        return;
    }
    {
        int i = (bid - 5120) * 256 + threadIdx.x;
        if (i < 1536)
            qbias[i] = (i < 512) ? bq[i] : (i < 1024 ? bk[i - 512] : bv[i - 1024]);
    }
}

// ---------------------------------------------------------------------------
// bf16 MFMA GEMM (single-buffered, 2 barriers/K-iter, gload_lds staging) with
// COALESCED two-pass epilogue: acc(+bias) -> LDS bf16 -> short8 global stores
// (256B row segments), vectorized residual reads.
// BM = MI*32, BN = NI*32, BK = 64, 4 waves (2x2). bf16 output only.
// ---------------------------------------------------------------------------
template<int MI, int NI>
__global__ __launch_bounds__(256) void gemm2(
    const short* __restrict__ A, int lda,
    const short* __restrict__ Bt, int ldb,
    const float* __restrict__ bias,
    const float* __restrict__ residf,
    const short* __restrict__ residb,
    short* __restrict__ Cb,
    int N, int K, int relu)
{
    constexpr int BM = MI * 32;
    constexpr int BN = NI * 32;
    __shared__ short smem[BM * 64 + BN * 64];
    short* Ash = smem;
    short* Bsh = smem + BM * 64;
    int tid = threadIdx.x;
    int wid = tid >> 6, lane = tid & 63;
    int g = lane >> 4, c = lane & 15;
    int wm = wid >> 1, wn = wid & 1;
    size_t m0 = (size_t)blockIdx.x * BM;
    size_t n0 = (size_t)blockIdx.y * BN;
    int lrow = lane >> 3;          // 0..7
    int lcol = (lane & 7) * 8;     // shorts (16B granule)

    f32x4 acc[MI][NI];
#pragma unroll
    for (int i = 0; i < MI; ++i)
#pragma unroll
        for (int j = 0; j < NI; ++j)
            acc[i][j] = (f32x4){0.f, 0.f, 0.f, 0.f};

    for (int k0 = 0; k0 < K; k0 += 64) {
        __syncthreads();
#pragma unroll
        for (int i = 0; i < MI; ++i) {
            int chunk = wid * MI + i; int row = chunk * 8 + lrow;
            gload16(A + (m0 + row) * lda + k0 + lcol, Ash + chunk * 512);
        }
#pragma unroll
        for (int i = 0; i < NI; ++i) {
            int chunk = wid * NI + i; int row = chunk * 8 + lrow;
            gload16(Bt + (n0 + row) * ldb + k0 + lcol, Bsh + chunk * 512);
        }
        __syncthreads();

        short8 a[MI][2], b[NI][2];
#pragma unroll
        for (int kc = 0; kc < 2; ++kc) {
#pragma unroll
            for (int mi = 0; mi < MI; ++mi)
                a[mi][kc] = *(const short8*)&Ash[(wm * MI * 16 + mi * 16 + c) * 64 + kc * 32 + g * 8];
#pragma unroll
            for (int ni = 0; ni < NI; ++ni)
                b[ni][kc] = *(const short8*)&Bsh[(wn * NI * 16 + ni * 16 + c) * 64 + kc * 32 + g * 8];
        }
#pragma unroll
        for (int kc = 0; kc < 2; ++kc)
#pragma unroll
            for (int mi = 0; mi < MI; ++mi)
#pragma unroll
                for (int ni = 0; ni < NI; ++ni)
                    acc[mi][ni] = __builtin_amdgcn_mfma_f32_16x16x32_bf16(
                        a[mi][kc], b[ni][kc], acc[mi][ni], 0, 0, 0);
    }

    // ---- epilogue pass 1: acc (+bias) -> LDS bf16 [BM][BN] ----
    __syncthreads();                 // staging reads done; reuse smem
    short* Cl = smem;                // BM*BN <= BM*64 + BN*64 for our shapes
#pragma unroll
    for (int mi = 0; mi < MI; ++mi)
#pragma unroll
        for (int ni = 0; ni < NI; ++ni)
#pragma unroll
            for (int r = 0; r < 4; ++r) {
                int rl = wm * (MI * 16) + mi * 16 + g * 4 + r;
                int cl = wn * (NI * 16) + ni * 16 + c;
                float v = acc[mi][ni][r];
                if (bias) v += bias[n0 + cl];
                Cl[rl * BN + cl] = f2bf(v);
            }
    __syncthreads();

    // ---- epilogue pass 2: coalesced short8 stores + vector resid/relu ----
    constexpr int TOT = BM * BN;
#pragma unroll
    for (int i = tid * 8; i < TOT; i += 2048) {
        int row = i / BN, col = i - (i / BN) * BN;
        size_t gidx = (m0 + row) * (size_t)N + n0 + col;
        short8 vv = *(const short8*)&Cl[i];
        if (residf || residb || relu) {
            float tmp[8];
#pragma unroll
            for (int j = 0; j < 8; ++j) tmp[j] = b2f(vv[j]);
            if (residf) {
                float4 ra = *(const float4*)&residf[gidx];
                float4 rb = *(const float4*)&residf[gidx + 4];
                tmp[0] += ra.x; tmp[1] += ra.y; tmp[2] += ra.z; tmp[3] += ra.w;
                tmp[4] += rb.x; tmp[5] += rb.y; tmp[6] += rb.z; tmp[7] += rb.w;
            }
            if (residb) {
                short8 rr = *(const short8*)&residb[gidx];
#pragma unroll
                for (int j = 0; j < 8; ++j) tmp[j] += b2f(rr[j]);
            }
            if (relu)
#pragma unroll
                for (int j = 0; j < 8; ++j) tmp[j] = fmaxf(tmp[j], 0.f);
#pragma unroll
            for (int j = 0; j < 8; ++j) vv[j] = f2bf(tmp[j]);
        }
        *(short8*)&Cb[gidx] = vv;
    }
}

// ---------------------------------------------------------------------------
// Fused flash attention + full heatmap (plain heat stores).
// ---------------------------------------------------------------------------
__global__ __launch_bounds__(256) void attn_kernel(
    const short* __restrict__ QKV,
    float* __restrict__ heat,
    short* __restrict__ wv)
{
    constexpr int S = 2048, LD = 1536;
    __shared__ short Kl[2][4096];      // [buf][t][64] linear, 128B rows
    __shared__ short Vt[2][64][72];    // [buf][v][t]
    __shared__ short Pl[4][16][72];    // per-wave P, [s][t]

    int tid = threadIdx.x, wid = tid >> 6, lane = tid & 63;
    int g = lane >> 4, c = lane & 15, g4 = g * 4;
    int id = blockIdx.x;
    int xcd = id & 7, k = id >> 3;
    int hb = (xcd << 1) | (k >> 5);
    int sb = k & 31;
    int by = (sb & 1) ? (31 - (sb >> 1)) : (sb >> 1);
    int h = hb >> 1, b = hb & 1;
    int s0 = by * 64, sbase = s0 + wid * 16, sglob = sbase + c;

    const short* qp = QKV + (size_t)(b * S + sglob) * LD + h * 64 + g * 8;
    short8 q0 = *(const short8*)qp, q1 = *(const short8*)(qp + 32);

    f32x4 o[4];
#pragma unroll
    for (int ni = 0; ni < 4; ++ni) o[ni] = (f32x4){0.f, 0.f, 0.f, 0.f};
    float m_run = -1e30f, l_run = 0.f;

    const short* kb_base = QKV + (size_t)b * S * LD + 512 + h * 64;
    int vrow = tid >> 2, vch = tid & 3;
    const short* vb_base = QKV + (size_t)b * S * LD + 1024 + h * 64 + vch * 16;

    auto stageK = [&](int tt, int buf) {
        int j = lane & 7, rr = lane >> 3;
#pragma unroll
        for (int i = 0; i < 2; ++i) {
            int chunk = wid * 2 + i;
            int row = chunk * 8 + rr;
            gload16(kb_base + (size_t)(tt * 64 + row) * LD + j * 8,
                    &Kl[buf][chunk * 512]);
        }
    };
    auto loadK = [&](int tt, short8 dst[4][2]) {
#pragma unroll
        for (int ni = 0; ni < 4; ++ni)
#pragma unroll
            for (int kc = 0; kc < 2; ++kc)
                dst[ni][kc] = *(const short8*)(kb_base +
                    (size_t)(tt * 64 + ni * 16 + c) * LD + kc * 32 + g * 8);
    };

    stageK(0, 0);
    short8 va, vb2;
    {
        const short* vp = vb_base + (size_t)vrow * LD;
        va = *(const short8*)vp; vb2 = *(const short8*)(vp + 8);
    }
    __syncthreads();   // K(0) staged

    // ---- causal phase: tiles 0..by, 1 barrier/tile ----
    for (int tt = 0; tt <= by; ++tt) {
        int cur = tt & 1;
#pragma unroll
        for (int j = 0; j < 8; ++j) Vt[cur][vch * 16 + j][vrow] = va[j];
#pragma unroll
        for (int j = 0; j < 8; ++j) Vt[cur][vch * 16 + 8 + j][vrow] = vb2[j];

        short8 vna, vnb;
        if (tt < by) {
            stageK(tt + 1, cur ^ 1);   // async; drained by this tile's barrier
            const short* vp = vb_base + (size_t)((tt + 1) * 64 + vrow) * LD;
            vna = *(const short8*)vp; vnb = *(const short8*)(vp + 8);
        }

        short8 kf[4][2];
#pragma unroll
        for (int ni = 0; ni < 4; ++ni)
#pragma unroll
            for (int kc = 0; kc < 2; ++kc)
                kf[ni][kc] = *(const short8*)&Kl[cur][(ni * 16 + c) * 64 + kc * 32 + g * 8];

        int t0 = tt * 64;
        f32x4 sacc[4];
#pragma unroll
        for (int ni = 0; ni < 4; ++ni) {
            sacc[ni] = (f32x4){0.f, 0.f, 0.f, 0.f};
            sacc[ni] = __builtin_amdgcn_mfma_f32_16x16x32_bf16(kf[ni][0], q0, sacc[ni], 0, 0, 0);
            sacc[ni] = __builtin_amdgcn_mfma_f32_16x16x32_bf16(kf[ni][1], q1, sacc[ni], 0, 0, 0);
        }
#pragma unroll
        for (int ni = 0; ni < 4; ++ni)
            *(f32x4*)&heat[((size_t)hb * S + sglob) * S + t0 + ni * 16 + g4] = sacc[ni];

        float tm = -1e30f;
        if (tt == by) {   // diagonal tile: mask
#pragma unroll
            for (int ni = 0; ni < 4; ++ni)
#pragma unroll
                for (int r = 0; r < 4; ++r) {
                    int t = t0 + ni * 16 + g4 + r;
                    float v = (t <= sglob) ? sacc[ni][r] : -1e30f;
                    sacc[ni][r] = v;
                    tm = fmaxf(tm, v);
                }
        } else {          // interior: fully causal
#pragma unroll
            for (int ni = 0; ni < 4; ++ni)
#pragma unroll
                for (int r = 0; r < 4; ++r)
                    tm = fmaxf(tm, sacc[ni][r]);
        }
        tm = fmaxf(tm, __shfl_xor(tm, 16));
        tm = fmaxf(tm, __shfl_xor(tm, 32));

        float mn = fmaxf(m_run, tm);
        float sc = __expf(m_run - mn);
        m_run = mn;
        float ps = 0.f;
#pragma unroll
        for (int ni = 0; ni < 4; ++ni)
#pragma unroll
            for (int r = 0; r < 4; ++r) {
                float p = __expf(sacc[ni][r] - mn);
                sacc[ni][r] = p;
                ps += p;
            }
        ps += __shfl_xor(ps, 16);
        ps += __shfl_xor(ps, 32);
        l_run = l_run * sc + ps;

        float scr[4];
#pragma unroll
        for (int r = 0; r < 4; ++r) scr[r] = __shfl(sc, g4 + r, 64);
#pragma unroll
        for (int ni = 0; ni < 4; ++ni)
#pragma unroll
            for (int r = 0; r < 4; ++r)
                o[ni][r] *= scr[r];

#pragma unroll
        for (int ni = 0; ni < 4; ++ni) {
            short4 pw;
            pw.x = f2bf(sacc[ni][0]); pw.y = f2bf(sacc[ni][1]);
            pw.z = f2bf(sacc[ni][2]); pw.w = f2bf(sacc[ni][3]);
            *reinterpret_cast<short4*>(&Pl[wid][c][ni * 16 + g4]) = pw;
        }

        __syncthreads();   // Vt[cur]+Pl visible; K(tt+1) gload drained

        short8 pa0 = *reinterpret_cast<const short8*>(&Pl[wid][c][g * 8]);
        short8 pa1 = *reinterpret_cast<const short8*>(&Pl[wid][c][32 + g * 8]);
#pragma unroll
        for (int ni = 0; ni < 4; ++ni) {
            short8 vb0 = *reinterpret_cast<const short8*>(&Vt[cur][ni * 16 + c][g * 8]);
            short8 vb1 = *reinterpret_cast<const short8*>(&Vt[cur][ni * 16 + c][32 + g * 8]);
            o[ni] = __builtin_amdgcn_mfma_f32_16x16x32_bf16(pa0, vb0, o[ni], 0, 0, 0);
            o[ni] = __builtin_amdgcn_mfma_f32_16x16x32_bf16(pa1, vb1, o[ni], 0, 0, 0);
        }

        if (tt < by) { va = vna; vb2 = vnb; }
    }

    // final wv write (frees o/l before the streaming phase)
    {
        float linv[4];
#pragma unroll
        for (int r = 0; r < 4; ++r) linv[r] = 1.0f / __shfl(l_run, g4 + r, 64);
#pragma unroll
        for (int ni = 0; ni < 4; ++ni)
#pragma unroll
            for (int r = 0; r < 4; ++r) {
                float v = o[ni][r] * linv[r];
                wv[(size_t)(b * S + sbase + g4 + r) * 512 + h * 64 + ni * 16 + c] = f2bf(v);
            }
    }

    // ---- streaming phase: t-split across waves ----
    short8 qa[4][2];
#pragma unroll
    for (int si = 0; si < 4; ++si) {
        const short* qps = QKV + (size_t)(b * S + s0 + si * 16 + c) * LD + h * 64 + g * 8;
        qa[si][0] = *(const short8*)qps;
        qa[si][1] = *(const short8*)(qps + 32);
    }

    for (int tt = by + 1 + wid; tt < 32; tt += 4) {
        int t0 = tt * 64;
        short8 kf[4][2];
        loadK(tt, kf);
        f32x4 sc4[4][4];
#pragma unroll
        for (int si = 0; si < 4; ++si)
#pragma unroll
            for (int ni = 0; ni < 4; ++ni) {
                sc4[si][ni] = (f32x4){0.f, 0.f, 0.f, 0.f};
                sc4[si][ni] = __builtin_amdgcn_mfma_f32_16x16x32_bf16(
                    kf[ni][0], qa[si][0], sc4[si][ni], 0, 0, 0);
                sc4[si][ni] = __builtin_amdgcn_mfma_f32_16x16x32_bf16(
                    kf[ni][1], qa[si][1], sc4[si][ni], 0, 0, 0);
            }
#pragma unroll
        for (int si = 0; si < 4; ++si)
#pragma unroll
            for (int ni = 0; ni < 4; ++ni)
                *(f32x4*)&heat[((size_t)hb * S + s0 + si * 16 + c) * S + t0 + ni * 16 + g4] = sc4[si][ni];
    }
}

// ---------------------------------------------------------------------------
// LayerNorm over last dim 512, bf16 input; fp32 and/or bf16 output.
// ---------------------------------------------------------------------------
__device__ __forceinline__ float block_sum256(float v, float* sm) {
#pragma unroll
    for (int off = 32; off; off >>= 1) v += __shfl_down(v, off);
    __syncthreads();
    if ((threadIdx.x & 63) == 0) sm[threadIdx.x >> 6] = v;
    __syncthreads();
    return sm[0] + sm[1] + sm[2] + sm[3];
}

__global__ __launch_bounds__(256) void ln_kernel(
    const short* __restrict__ in, const float* __restrict__ g,
    const float* __restrict__ bta, float* __restrict__ outf,
    short* __restrict__ outb)
{
    __shared__ float sm[4];
    int row = blockIdx.x, tid = threadIdx.x;
    const short* r = in + (size_t)row * 512;
    float v0 = b2f(r[tid]), v1 = b2f(r[tid + 256]);
    float mu = block_sum256(v0 + v1, sm) * (1.f / 512.f);
    float d0 = v0 - mu, d1 = v1 - mu;
    float var = block_sum256(d0 * d0 + d1 * d1, sm) * (1.f / 512.f);
    float rs = rsqrtf(var + 1e-5f);
    float o0 = d0 * rs * g[tid] + bta[tid];
    float o1 = d1 * rs * g[tid + 256] + bta[tid + 256];
    if (outf) {
        outf[(size_t)row * 512 + tid]       = o0;
        outf[(size_t)row * 512 + tid + 256] = o1;
    }
    if (outb) {
        outb[(size_t)row * 512 + tid]       = f2bf(o0);
        outb[(size_t)row * 512 + tid + 256] = f2bf(o1);
    }
}

// ---------------------------------------------------------------------------
extern "C" void kernel_launch(void* const* d_in, const int* in_sizes, int n_in,
                              void* d_out, int out_size, void* d_ws, size_t ws_size,
                              hipStream_t stream)
{
    const float* x    = (const float*)d_in[0];
    const float* Wq   = (const float*)d_in[1];
    const float* bq   = (const float*)d_in[2];
    const float* Wk   = (const float*)d_in[3];
    const float* bk   = (const float*)d_in[4];
    const float* Wv   = (const float*)d_in[5];
    const float* bv   = (const float*)d_in[6];
    const float* Wo   = (const float*)d_in[7];
    const float* bo   = (const float*)d_in[8];
    const float* W1   = (const float*)d_in[9];
    const float* b1   = (const float*)d_in[10];
    const float* W2   = (const float*)d_in[11];
    const float* b2   = (const float*)d_in[12];
    const float* ln1g = (const float*)d_in[13];
    const float* ln1b = (const float*)d_in[14];
    const float* ln2g = (const float*)d_in[15];
    const float* ln2b = (const float*)d_in[16];

    const int T = 4096;

    char* w = (char*)d_ws;
    short* xb     = (short*)(w);                     // [0,4M)
    short* QKVb   = (short*)(w + 4194304);           // [4M,16M)
    short* wvb    = (short*)(w + 16777216);          // [16M,20M)
    short* tmpb   = (short*)(w + 20971520);          // [20M,24M) bf16
    short* x1b    = (short*)(w + 25165824);          // [24M,28M)
    short* tmpb2  = (short*)(w + 29360128);          // [28M,32M)
    short* Wqkv_t = (short*)(w + 33554432);          // [32M,33.5M)
    short* Wo_t   = (short*)(w + 35127296);
    short* W1_t   = (short*)(w + 35651584);
    short* W2_t   = (short*)(w + 37748736);
    float* qbias  = (float*)(w + 39845888);
    short* hidb   = (short*)(w);                     // aliases xb+QKVb (dead by FFN1)

    float* out_x2 = (float*)d_out;
    float* heat   = out_x2 + (size_t)T * 512;

    prep_kernel<<<dim3(5126), 256, 0, stream>>>(
        x, xb, Wq, Wk, Wv, Wo, W1, W2,
        Wqkv_t, Wo_t, W1_t, W2_t, bq, bk, bv, qbias);

    // QKV projection (combined, N=1536)
    gemm2<2, 4><<<dim3(64, 12), 256, 0, stream>>>(
        xb, 512, Wqkv_t, 512, qbias, nullptr, nullptr, QKVb, 1536, 512, 0);

    // fused attention + heatmap
    attn_kernel<<<dim3(512), 256, 0, stream>>>(QKVb, heat, wvb);

    // Wo projection + residual (fp32 x), bf16 out
    gemm2<2, 2><<<dim3(64, 8), 256, 0, stream>>>(
        wvb, 512, Wo_t, 512, bo, x, nullptr, tmpb, 512, 512, 0);
    ln_kernel<<<dim3(T), 256, 0, stream>>>(tmpb, ln1g, ln1b, nullptr, x1b);

    // FFN
    gemm2<2, 4><<<dim3(64, 16), 256, 0, stream>>>(
        x1b, 512, W1_t, 512, b1, nullptr, nullptr, hidb, 2048, 512, 1);
    gemm2<2, 2><<<dim3(64, 8), 256, 0, stream>>>(
        hidb, 2048, W2_t, 2048, b2, nullptr, x1b, tmpb2, 512, 2048, 0);
    ln_kernel<<<dim3(T), 256, 0, stream>>>(tmpb2, ln2g, ln2b, out_x2, nullptr);
}